// Round 9
// baseline (325.308 us; speedup 1.0000x reference)
//
#include <hip/hip_runtime.h>

#define D 64
#define P 8   // histogram privatization factor; key = dst*P + (thread & (P-1))

// ---- bf16 helpers (RNE), raw ushort storage ------------------------------
__device__ __forceinline__ unsigned short f2bf(float f) {
    unsigned u = __float_as_uint(f);
    unsigned r = (u + 0x7FFFu + ((u >> 16) & 1u)) >> 16;
    return (unsigned short)r;
}
__device__ __forceinline__ float bf2f(unsigned short h) {
    return __uint_as_float((unsigned)h << 16);
}

// ================= CSR build: privatized hist + rank ========================
__global__ void hist_rank_kernel(const int* __restrict__ dst, int* __restrict__ deg,
                                 int* __restrict__ rank, int E) {
    int i = blockIdx.x * blockDim.x + threadIdx.x;
    int part = i & (P - 1);
    int base = i * 8;
    if (base + 8 <= E) {
        int4 d0 = *reinterpret_cast<const int4*>(dst + base);
        int4 d1 = *reinterpret_cast<const int4*>(dst + base + 4);
        int4 r0, r1;                       // 8 independent atomic chains
        r0.x = atomicAdd(&deg[d0.x * P + part], 1);
        r0.y = atomicAdd(&deg[d0.y * P + part], 1);
        r0.z = atomicAdd(&deg[d0.z * P + part], 1);
        r0.w = atomicAdd(&deg[d0.w * P + part], 1);
        r1.x = atomicAdd(&deg[d1.x * P + part], 1);
        r1.y = atomicAdd(&deg[d1.y * P + part], 1);
        r1.z = atomicAdd(&deg[d1.z * P + part], 1);
        r1.w = atomicAdd(&deg[d1.w * P + part], 1);
        *reinterpret_cast<int4*>(rank + base) = r0;
        *reinterpret_cast<int4*>(rank + base + 4) = r1;
    } else {
        for (int e = base; e < E; ++e)
            rank[e] = atomicAdd(&deg[dst[e] * P + part], 1);
    }
}

// --- scan over NK = N*P bins; 512-thread blocks so block count <= 1024 ------
__global__ void scan_k1(const int* __restrict__ deg, int* __restrict__ bsum, int n) {
    __shared__ int sh[512];
    int t = threadIdx.x;
    int g = blockIdx.x * 512 + t;
    int v = (g < n) ? deg[g] : 0;
    sh[t] = v;
    __syncthreads();
    for (int off = 1; off < 512; off <<= 1) {
        int u = (t >= off) ? sh[t - off] : 0;
        __syncthreads();
        sh[t] += u;
        __syncthreads();
    }
    if (t == 511) bsum[blockIdx.x] = sh[511];
}

__global__ void scan_k2(const int* __restrict__ bsum, int* __restrict__ boff, int nb) {
    __shared__ int sh[1024];
    int t = threadIdx.x;
    int v = (t < nb) ? bsum[t] : 0;
    sh[t] = v;
    __syncthreads();
    for (int off = 1; off < 1024; off <<= 1) {
        int u = (t >= off) ? sh[t - off] : 0;
        __syncthreads();
        sh[t] += u;
        __syncthreads();
    }
    if (t < nb) boff[t] = sh[t] - v;
}

__global__ void scan_k3(const int* __restrict__ deg, const int* __restrict__ boff,
                        int* __restrict__ row_ptr, int n) {
    __shared__ int sh[512];
    int t = threadIdx.x;
    int g = blockIdx.x * 512 + t;
    int v = (g < n) ? deg[g] : 0;
    sh[t] = v;
    __syncthreads();
    for (int off = 1; off < 512; off <<= 1) {
        int u = (t >= off) ? sh[t - off] : 0;
        __syncthreads();
        sh[t] += u;
        __syncthreads();
    }
    if (g < n) {
        int excl = sh[t] - v + boff[blockIdx.x];
        row_ptr[g] = excl;
        if (g == n - 1) row_ptr[n] = excl + v;
    }
}

// atomic-free permutation: pos = row_ptr[dst*P + part] + rank
__global__ void perm_rank_kernel(const int* __restrict__ src, const int* __restrict__ dst,
                                 const int* __restrict__ rank, const int* __restrict__ row_ptr,
                                 int* __restrict__ sorted_src, int E) {
    int i = blockIdx.x * blockDim.x + threadIdx.x;
    int part = i & (P - 1);
    int base = i * 8;
    if (base + 8 <= E) {
        int4 d0 = *reinterpret_cast<const int4*>(dst + base);
        int4 d1 = *reinterpret_cast<const int4*>(dst + base + 4);
        int4 s0 = *reinterpret_cast<const int4*>(src + base);
        int4 s1 = *reinterpret_cast<const int4*>(src + base + 4);
        int4 r0 = *reinterpret_cast<const int4*>(rank + base);
        int4 r1 = *reinterpret_cast<const int4*>(rank + base + 4);
        int p0 = row_ptr[d0.x * P + part] + r0.x;
        int p1 = row_ptr[d0.y * P + part] + r0.y;
        int p2 = row_ptr[d0.z * P + part] + r0.z;
        int p3 = row_ptr[d0.w * P + part] + r0.w;
        int p4 = row_ptr[d1.x * P + part] + r1.x;
        int p5 = row_ptr[d1.y * P + part] + r1.y;
        int p6 = row_ptr[d1.z * P + part] + r1.z;
        int p7 = row_ptr[d1.w * P + part] + r1.w;
        __builtin_nontemporal_store(s0.x, &sorted_src[p0]);
        __builtin_nontemporal_store(s0.y, &sorted_src[p1]);
        __builtin_nontemporal_store(s0.z, &sorted_src[p2]);
        __builtin_nontemporal_store(s0.w, &sorted_src[p3]);
        __builtin_nontemporal_store(s1.x, &sorted_src[p4]);
        __builtin_nontemporal_store(s1.y, &sorted_src[p5]);
        __builtin_nontemporal_store(s1.z, &sorted_src[p6]);
        __builtin_nontemporal_store(s1.w, &sorted_src[p7]);
    } else {
        for (int e = base; e < E; ++e)
            sorted_src[row_ptr[dst[e] * P + part] + rank[e]] = src[e];
    }
}

// ================= x (fp32) -> Xb (bf16) ====================================
__global__ void convert_kernel(const float* __restrict__ x, unsigned short* __restrict__ xb,
                               int total) {
    int i = blockIdx.x * blockDim.x + threadIdx.x;
    int base = i * 4;
    if (base + 4 <= total) {
        float4 v = *reinterpret_cast<const float4*>(x + base);
        ushort4 o;
        o.x = f2bf(v.x); o.y = f2bf(v.y); o.z = f2bf(v.z); o.w = f2bf(v.w);
        *reinterpret_cast<ushort4*>(xb + base) = o;
    } else {
        for (int k = base; k < total; ++k) xb[k] = f2bf(x[k]);
    }
}

// ====== gather: whole row = bins [n*P, (n+1)*P) contiguous ==================
// aggb[n] (bf16) = sum_{e in row n} bf16row(xb[src_e])  (fp32 accumulate)
__global__ void __launch_bounds__(256)
gather_bf16(const unsigned short* __restrict__ xb,
            const int* __restrict__ row_ptr,
            const int* __restrict__ sorted_src,
            unsigned short* __restrict__ aggb, int n_nodes) {
    int lane = threadIdx.x & 63;
    int n = blockIdx.x * (blockDim.x >> 6) + (threadIdx.x >> 6);
    if (n >= n_nodes) return;
    int g = lane >> 4;          // edge slot within a 4-edge step
    int j = lane & 15;          // feature-quad index (features 4j..4j+3)

    int beg = row_ptr[n * P];
    int end = row_ptr[n * P + P];

    float ax0=0.f, ay0=0.f, az0=0.f, aw0=0.f;
    float ax1=0.f, ay1=0.f, az1=0.f, aw1=0.f;
    float ax2=0.f, ay2=0.f, az2=0.f, aw2=0.f;
    float ax3=0.f, ay3=0.f, az3=0.f, aw3=0.f;

    int e = beg + g;
    for (; e + 12 < end; e += 16) {           // ILP-4 per group
        int s0 = sorted_src[e];
        int s1 = sorted_src[e + 4];
        int s2 = sorted_src[e + 8];
        int s3 = sorted_src[e + 12];
        uint2 u0 = *reinterpret_cast<const uint2*>(xb + (((size_t)(unsigned)s0) << 6) + (j << 2));
        uint2 u1 = *reinterpret_cast<const uint2*>(xb + (((size_t)(unsigned)s1) << 6) + (j << 2));
        uint2 u2 = *reinterpret_cast<const uint2*>(xb + (((size_t)(unsigned)s2) << 6) + (j << 2));
        uint2 u3 = *reinterpret_cast<const uint2*>(xb + (((size_t)(unsigned)s3) << 6) + (j << 2));
        ax0 += __uint_as_float(u0.x << 16); ay0 += __uint_as_float(u0.x & 0xFFFF0000u);
        az0 += __uint_as_float(u0.y << 16); aw0 += __uint_as_float(u0.y & 0xFFFF0000u);
        ax1 += __uint_as_float(u1.x << 16); ay1 += __uint_as_float(u1.x & 0xFFFF0000u);
        az1 += __uint_as_float(u1.y << 16); aw1 += __uint_as_float(u1.y & 0xFFFF0000u);
        ax2 += __uint_as_float(u2.x << 16); ay2 += __uint_as_float(u2.x & 0xFFFF0000u);
        az2 += __uint_as_float(u2.y << 16); aw2 += __uint_as_float(u2.y & 0xFFFF0000u);
        ax3 += __uint_as_float(u3.x << 16); ay3 += __uint_as_float(u3.x & 0xFFFF0000u);
        az3 += __uint_as_float(u3.y << 16); aw3 += __uint_as_float(u3.y & 0xFFFF0000u);
    }
    for (; e < end; e += 4) {
        int s0 = sorted_src[e];
        uint2 u0 = *reinterpret_cast<const uint2*>(xb + (((size_t)(unsigned)s0) << 6) + (j << 2));
        ax0 += __uint_as_float(u0.x << 16); ay0 += __uint_as_float(u0.x & 0xFFFF0000u);
        az0 += __uint_as_float(u0.y << 16); aw0 += __uint_as_float(u0.y & 0xFFFF0000u);
    }
    float ax = (ax0 + ax1) + (ax2 + ax3);
    float ay = (ay0 + ay1) + (ay2 + ay3);
    float az = (az0 + az1) + (az2 + az3);
    float aw = (aw0 + aw1) + (aw2 + aw3);
    ax += __shfl_xor(ax, 16); ay += __shfl_xor(ay, 16);
    az += __shfl_xor(az, 16); aw += __shfl_xor(aw, 16);
    ax += __shfl_xor(ax, 32); ay += __shfl_xor(ay, 32);
    az += __shfl_xor(az, 32); aw += __shfl_xor(aw, 32);

    if (g == 0) {
        uint2 o;
        o.x = (unsigned)f2bf(ax) | ((unsigned)f2bf(ay) << 16);
        o.y = (unsigned)f2bf(az) | ((unsigned)f2bf(aw) << 16);
        *reinterpret_cast<uint2*>(aggb + (((size_t)(unsigned)n) << 6) + (j << 2)) = o;
    }
}

// ====== dense: y[n] = xb[n]@Ws + aggb[n]@Wm + b =============================
__global__ void __launch_bounds__(256)
dense_v3(const unsigned short* __restrict__ xb,
         const unsigned short* __restrict__ aggb,
         const float* __restrict__ Wself,
         const float* __restrict__ Wmsg,
         const float* __restrict__ bias,
         float* __restrict__ out_f32,
         unsigned short* __restrict__ out_bf16,
         int n_nodes, int last) {
    int lane = threadIdx.x & 63;
    int wave = threadIdx.x >> 6;
    int wpb = blockDim.x >> 6;

    float Wsc[D], Wmc[D];
#pragma unroll
    for (int k = 0; k < D; ++k) {
        Wsc[k] = Wself[k * D + lane];
        Wmc[k] = Wmsg[k * D + lane];
    }
    float bj = bias[lane];

    for (int n0 = blockIdx.x * wpb + wave; n0 < n_nodes; n0 += gridDim.x * wpb) {
        int n = __builtin_amdgcn_readfirstlane(n0);
        const unsigned* xrow = reinterpret_cast<const unsigned*>(xb)   + ((size_t)(unsigned)n << 5);
        const unsigned* arow = reinterpret_cast<const unsigned*>(aggb) + ((size_t)(unsigned)n << 5);

        float acc0 = bj, acc1 = 0.f, acc2 = 0.f, acc3 = 0.f;
#pragma unroll
        for (int dq = 0; dq < 32; dq += 2) {
            unsigned xu0 = xrow[dq], xu1 = xrow[dq + 1];
            unsigned au0 = arow[dq], au1 = arow[dq + 1];
            acc0 = fmaf(__uint_as_float(xu0 << 16),         Wsc[2 * dq + 0], acc0);
            acc1 = fmaf(__uint_as_float(xu0 & 0xFFFF0000u), Wsc[2 * dq + 1], acc1);
            acc2 = fmaf(__uint_as_float(xu1 << 16),         Wsc[2 * dq + 2], acc2);
            acc3 = fmaf(__uint_as_float(xu1 & 0xFFFF0000u), Wsc[2 * dq + 3], acc3);
            acc0 = fmaf(__uint_as_float(au0 << 16),         Wmc[2 * dq + 0], acc0);
            acc1 = fmaf(__uint_as_float(au0 & 0xFFFF0000u), Wmc[2 * dq + 1], acc1);
            acc2 = fmaf(__uint_as_float(au1 << 16),         Wmc[2 * dq + 2], acc2);
            acc3 = fmaf(__uint_as_float(au1 & 0xFFFF0000u), Wmc[2 * dq + 3], acc3);
        }
        float acc = (acc0 + acc1) + (acc2 + acc3);
        if (last) {
            out_f32[((size_t)(unsigned)n << 6) + lane] = acc;
        } else {
            out_bf16[((size_t)(unsigned)n << 6) + lane] = f2bf(fmaxf(acc, 0.f));
        }
    }
}

// ================= fallback (atomic path, fp32-exact) =======================
__global__ void scatter_kernel(const float* __restrict__ x,
                               const int* __restrict__ src,
                               const int* __restrict__ dst,
                               float* __restrict__ agg, int n_edges) {
    int e = blockIdx.x * (blockDim.x >> 6) + (threadIdx.x >> 6);
    int lane = threadIdx.x & 63;
    if (e >= n_edges) return;
    float v = x[(size_t)src[e] * D + lane];
    unsafeAtomicAdd(&agg[(size_t)dst[e] * D + lane], v);
}

__global__ void dense_kernel(const float* __restrict__ xin,
                             const float* __restrict__ agg,
                             const float* __restrict__ Wself,
                             const float* __restrict__ Wmsg,
                             const float* __restrict__ bias,
                             float* __restrict__ xout,
                             int n_nodes, int do_relu) {
    __shared__ float Ws[D * D];
    __shared__ float Wm[D * D];
    for (int i = threadIdx.x; i < D * D; i += blockDim.x) {
        Ws[i] = Wself[i];
        Wm[i] = Wmsg[i];
    }
    __syncthreads();
    int lane = threadIdx.x & 63;
    int wave = threadIdx.x >> 6;
    int wpb = blockDim.x >> 6;
    float bj = bias[lane];
    for (int n = blockIdx.x * wpb + wave; n < n_nodes; n += gridDim.x * wpb) {
        float xv = xin[(size_t)n * D + lane];
        float av = agg[(size_t)n * D + lane];
        float acc = bj;
#pragma unroll
        for (int k = 0; k < D; ++k) {
            acc += __shfl(xv, k, 64) * Ws[k * D + lane]
                 + __shfl(av, k, 64) * Wm[k * D + lane];
        }
        if (do_relu) acc = fmaxf(acc, 0.f);
        xout[(size_t)n * D + lane] = acc;
    }
}

// ============================================================================
extern "C" void kernel_launch(void* const* d_in, const int* in_sizes, int n_in,
                              void* d_out, int out_size, void* d_ws, size_t ws_size,
                              hipStream_t stream) {
    const float* x0    = (const float*)d_in[0];
    const int*   ei    = (const int*)d_in[1];
    const float* Wmsg  = (const float*)d_in[2];
    const float* Wself = (const float*)d_in[3];
    const float* bias  = (const float*)d_in[4];
    float* out = (float*)d_out;

    const int N = in_sizes[0] / D;         // 50000
    const int E = in_sizes[1] / 2;         // 800000
    const int n_layers = in_sizes[4] / D;  // 3

    const int* src = ei;
    const int* dst = ei + E;
    const size_t NB = (size_t)N * D * sizeof(float);

    const int NK = N * P;                  // privatized bins
    const int NBB = (NK + 511) / 512;      // scan blocks (512-wide)
    const size_t need = (size_t)N * D * 2          // Xb
                      + (size_t)N * D * 2          // Aggb
                      + (size_t)E * 4              // sorted_src
                      + (size_t)E * 4              // rank
                      + (size_t)(NK + 1) * 4       // row_ptr
                      + (size_t)NK * 4             // deg
                      + (size_t)NBB * 4 * 2 + 256; // bsum + boff + slack

    if (ws_size >= need && NBB <= 1024) {
        char* p = (char*)d_ws;
        unsigned short* Xb   = (unsigned short*)p;  p += (size_t)N * D * 2;
        unsigned short* Aggb = (unsigned short*)p;  p += (size_t)N * D * 2;
        int* sorted_src      = (int*)p;             p += (size_t)E * 4;
        int* rank            = (int*)p;             p += (size_t)E * 4;
        int* row_ptr         = (int*)p;             p += (size_t)(NK + 1) * 4;
        int* deg             = (int*)p;             p += (size_t)NK * 4;
        int* bsum            = (int*)p;             p += (size_t)NBB * 4;
        int* boff            = (int*)p;

        hipMemsetAsync(deg, 0, (size_t)NK * 4, stream);
        {
            int threads = 256;
            int nthr = (E + 7) / 8;
            int blocks = (nthr + threads - 1) / threads;
            hist_rank_kernel<<<blocks, threads, 0, stream>>>(dst, deg, rank, E);
            scan_k1<<<NBB, 512, 0, stream>>>(deg, bsum, NK);
            scan_k2<<<1, 1024, 0, stream>>>(bsum, boff, NBB);
            scan_k3<<<NBB, 512, 0, stream>>>(deg, boff, row_ptr, NK);
            perm_rank_kernel<<<blocks, threads, 0, stream>>>(src, dst, rank, row_ptr,
                                                             sorted_src, E);
        }
        {
            int total = N * D;
            int nthr = (total + 3) / 4;
            convert_kernel<<<(nthr + 255) / 256, 256, 0, stream>>>(x0, Xb, total);
        }

        const int gather_blocks = (N + 3) / 4;   // one wave per node
        const int dense_blocks = 1024;

        for (int layer = 0; layer < n_layers; ++layer) {
            gather_bf16<<<gather_blocks, 256, 0, stream>>>(Xb, row_ptr, sorted_src, Aggb, N);
            dense_v3<<<dense_blocks, 256, 0, stream>>>(
                Xb, Aggb,
                Wself + (size_t)layer * D * D,
                Wmsg  + (size_t)layer * D * D,
                bias  + (size_t)layer * D,
                out, Xb, N, (layer == n_layers - 1) ? 1 : 0);
        }
    } else {
        // fallback: fp32 atomic path
        float* agg = (float*)d_ws;
        const int EPB = 256 / 64;
        const int scatter_blocks = (E + EPB - 1) / EPB;
        for (int layer = 0; layer < n_layers; ++layer) {
            hipMemsetAsync(agg, 0, NB, stream);
            const float* xin = (layer == 0) ? x0 : out;
            scatter_kernel<<<scatter_blocks, 256, 0, stream>>>(xin, src, dst, agg, E);
            dense_kernel<<<1024, 256, 0, stream>>>(
                xin, agg,
                Wself + (size_t)layer * D * D,
                Wmsg  + (size_t)layer * D * D,
                bias  + (size_t)layer * D,
                out, N, (layer < n_layers - 1) ? 1 : 0);
        }
    }
}

// Round 10
// 310.131 us; speedup vs baseline: 1.0489x; 1.0489x over previous
//
#include <hip/hip_runtime.h>

#define D 64

// ---- bf16 helpers (RNE), raw ushort storage ------------------------------
__device__ __forceinline__ unsigned short f2bf(float f) {
    unsigned u = __float_as_uint(f);
    unsigned r = (u + 0x7FFFu + ((u >> 16) & 1u)) >> 16;
    return (unsigned short)r;
}
__device__ __forceinline__ float bf2f(unsigned short h) {
    return __uint_as_float((unsigned)h << 16);
}

// ============ prep: zero deg + convert x (fp32) -> Xb (bf16) ================
__global__ void prep_kernel(const float* __restrict__ x, unsigned short* __restrict__ xb,
                            int total, int* __restrict__ deg, int N) {
    int i = blockIdx.x * blockDim.x + threadIdx.x;
    if (i < N) deg[i] = 0;
    int base = i * 4;
    if (base + 4 <= total) {
        float4 v = *reinterpret_cast<const float4*>(x + base);
        ushort4 o;
        o.x = f2bf(v.x); o.y = f2bf(v.y); o.z = f2bf(v.z); o.w = f2bf(v.w);
        *reinterpret_cast<ushort4*>(xb + base) = o;
    } else if (base < total) {
        for (int k = base; k < total; ++k) xb[k] = f2bf(x[k]);
    }
}

// ================= CSR build: hist captures per-edge rank ===================
__global__ void hist_rank_kernel(const int* __restrict__ dst, int* __restrict__ deg,
                                 int* __restrict__ rank, int E) {
    int i = blockIdx.x * blockDim.x + threadIdx.x;
    int base = i * 8;
    if (base + 8 <= E) {
        int4 d0 = *reinterpret_cast<const int4*>(dst + base);
        int4 d1 = *reinterpret_cast<const int4*>(dst + base + 4);
        int4 r0, r1;                       // 8 independent atomic chains
        r0.x = atomicAdd(&deg[d0.x], 1);
        r0.y = atomicAdd(&deg[d0.y], 1);
        r0.z = atomicAdd(&deg[d0.z], 1);
        r0.w = atomicAdd(&deg[d0.w], 1);
        r1.x = atomicAdd(&deg[d1.x], 1);
        r1.y = atomicAdd(&deg[d1.y], 1);
        r1.z = atomicAdd(&deg[d1.z], 1);
        r1.w = atomicAdd(&deg[d1.w], 1);
        *reinterpret_cast<int4*>(rank + base) = r0;
        *reinterpret_cast<int4*>(rank + base + 4) = r1;
    } else {
        for (int e = base; e < E; ++e) rank[e] = atomicAdd(&deg[dst[e]], 1);
    }
}

__global__ void scan_k1(const int* __restrict__ deg, int* __restrict__ bsum, int n) {
    __shared__ int sh[256];
    int t = threadIdx.x;
    int g = blockIdx.x * 256 + t;
    int v = (g < n) ? deg[g] : 0;
    sh[t] = v;
    __syncthreads();
    for (int off = 1; off < 256; off <<= 1) {
        int u = (t >= off) ? sh[t - off] : 0;
        __syncthreads();
        sh[t] += u;
        __syncthreads();
    }
    if (t == 255) bsum[blockIdx.x] = sh[255];
}

__global__ void scan_k2(const int* __restrict__ bsum, int* __restrict__ boff, int nb) {
    __shared__ int sh[1024];
    int t = threadIdx.x;
    int v = (t < nb) ? bsum[t] : 0;
    sh[t] = v;
    __syncthreads();
    for (int off = 1; off < 1024; off <<= 1) {
        int u = (t >= off) ? sh[t - off] : 0;
        __syncthreads();
        sh[t] += u;
        __syncthreads();
    }
    if (t < nb) boff[t] = sh[t] - v;
}

__global__ void scan_k3(const int* __restrict__ deg, const int* __restrict__ boff,
                        int* __restrict__ row_ptr, int n) {
    __shared__ int sh[256];
    int t = threadIdx.x;
    int g = blockIdx.x * 256 + t;
    int v = (g < n) ? deg[g] : 0;
    sh[t] = v;
    __syncthreads();
    for (int off = 1; off < 256; off <<= 1) {
        int u = (t >= off) ? sh[t - off] : 0;
        __syncthreads();
        sh[t] += u;
        __syncthreads();
    }
    if (g < n) {
        int excl = sh[t] - v + boff[blockIdx.x];
        row_ptr[g] = excl;
        if (g == n - 1) row_ptr[n] = excl + v;
    }
}

// atomic-free permutation: pos = row_ptr[dst] + rank
__global__ void perm_rank_kernel(const int* __restrict__ src, const int* __restrict__ dst,
                                 const int* __restrict__ rank, const int* __restrict__ row_ptr,
                                 int* __restrict__ sorted_src, int E) {
    int i = blockIdx.x * blockDim.x + threadIdx.x;
    int base = i * 8;
    if (base + 8 <= E) {
        int4 d0 = *reinterpret_cast<const int4*>(dst + base);
        int4 d1 = *reinterpret_cast<const int4*>(dst + base + 4);
        int4 s0 = *reinterpret_cast<const int4*>(src + base);
        int4 s1 = *reinterpret_cast<const int4*>(src + base + 4);
        int4 r0 = *reinterpret_cast<const int4*>(rank + base);
        int4 r1 = *reinterpret_cast<const int4*>(rank + base + 4);
        int p0 = row_ptr[d0.x] + r0.x;
        int p1 = row_ptr[d0.y] + r0.y;
        int p2 = row_ptr[d0.z] + r0.z;
        int p3 = row_ptr[d0.w] + r0.w;
        int p4 = row_ptr[d1.x] + r1.x;
        int p5 = row_ptr[d1.y] + r1.y;
        int p6 = row_ptr[d1.z] + r1.z;
        int p7 = row_ptr[d1.w] + r1.w;
        __builtin_nontemporal_store(s0.x, &sorted_src[p0]);
        __builtin_nontemporal_store(s0.y, &sorted_src[p1]);
        __builtin_nontemporal_store(s0.z, &sorted_src[p2]);
        __builtin_nontemporal_store(s0.w, &sorted_src[p3]);
        __builtin_nontemporal_store(s1.x, &sorted_src[p4]);
        __builtin_nontemporal_store(s1.y, &sorted_src[p5]);
        __builtin_nontemporal_store(s1.z, &sorted_src[p6]);
        __builtin_nontemporal_store(s1.w, &sorted_src[p7]);
    } else {
        for (int e = base; e < E; ++e)
            sorted_src[row_ptr[dst[e]] + rank[e]] = src[e];
    }
}

// ====== gather v4: predicated parallel tail (max 2 dependent chain rounds) ==
// aggb[n] (bf16) = sum_{e in row n} bf16row(xb[src_e])  (fp32 accumulate)
__global__ void __launch_bounds__(256)
gather_bf16(const unsigned short* __restrict__ xb,
            const int* __restrict__ row_ptr,
            const int* __restrict__ sorted_src,
            unsigned short* __restrict__ aggb, int n_nodes, int E) {
    int lane = threadIdx.x & 63;
    int n = blockIdx.x * (blockDim.x >> 6) + (threadIdx.x >> 6);
    if (n >= n_nodes) return;
    int g = lane >> 4;          // edge slot within a 4-edge step
    int j = lane & 15;          // feature-quad index (features 4j..4j+3)

    int beg = row_ptr[n];
    int end = row_ptr[n + 1];

    float ax0=0.f, ay0=0.f, az0=0.f, aw0=0.f;
    float ax1=0.f, ay1=0.f, az1=0.f, aw1=0.f;
    float ax2=0.f, ay2=0.f, az2=0.f, aw2=0.f;
    float ax3=0.f, ay3=0.f, az3=0.f, aw3=0.f;

    int e = beg + g;
    // main: 16 edges per iteration, 4 independent loads per group (ILP-4)
    for (; e + 12 < end; e += 16) {
        int s0 = sorted_src[e];
        int s1 = sorted_src[e + 4];
        int s2 = sorted_src[e + 8];
        int s3 = sorted_src[e + 12];
        uint2 u0 = *reinterpret_cast<const uint2*>(xb + (((size_t)(unsigned)s0) << 6) + (j << 2));
        uint2 u1 = *reinterpret_cast<const uint2*>(xb + (((size_t)(unsigned)s1) << 6) + (j << 2));
        uint2 u2 = *reinterpret_cast<const uint2*>(xb + (((size_t)(unsigned)s2) << 6) + (j << 2));
        uint2 u3 = *reinterpret_cast<const uint2*>(xb + (((size_t)(unsigned)s3) << 6) + (j << 2));
        ax0 += __uint_as_float(u0.x << 16); ay0 += __uint_as_float(u0.x & 0xFFFF0000u);
        az0 += __uint_as_float(u0.y << 16); aw0 += __uint_as_float(u0.y & 0xFFFF0000u);
        ax1 += __uint_as_float(u1.x << 16); ay1 += __uint_as_float(u1.x & 0xFFFF0000u);
        az1 += __uint_as_float(u1.y << 16); aw1 += __uint_as_float(u1.y & 0xFFFF0000u);
        ax2 += __uint_as_float(u2.x << 16); ay2 += __uint_as_float(u2.x & 0xFFFF0000u);
        az2 += __uint_as_float(u2.y << 16); aw2 += __uint_as_float(u2.y & 0xFFFF0000u);
        ax3 += __uint_as_float(u3.x << 16); ay3 += __uint_as_float(u3.x & 0xFFFF0000u);
        az3 += __uint_as_float(u3.y << 16); aw3 += __uint_as_float(u3.y & 0xFFFF0000u);
    }
    // tail: up to 3 slots (<=12 edges), ALL independent; clamped idx + masked add
    {
        int e1 = e + 4, e2 = e + 8;
        bool q0 = e  < end;
        bool q1 = e1 < end;
        bool q2 = e2 < end;
        int c0 = min(e,  E - 1);
        int c1 = min(e1, E - 1);
        int c2 = min(e2, E - 1);
        int s0 = sorted_src[c0];
        int s1 = sorted_src[c1];
        int s2 = sorted_src[c2];
        uint2 u0 = *reinterpret_cast<const uint2*>(xb + (((size_t)(unsigned)s0) << 6) + (j << 2));
        uint2 u1 = *reinterpret_cast<const uint2*>(xb + (((size_t)(unsigned)s1) << 6) + (j << 2));
        uint2 u2 = *reinterpret_cast<const uint2*>(xb + (((size_t)(unsigned)s2) << 6) + (j << 2));
        if (q0) {
            ax0 += __uint_as_float(u0.x << 16); ay0 += __uint_as_float(u0.x & 0xFFFF0000u);
            az0 += __uint_as_float(u0.y << 16); aw0 += __uint_as_float(u0.y & 0xFFFF0000u);
        }
        if (q1) {
            ax1 += __uint_as_float(u1.x << 16); ay1 += __uint_as_float(u1.x & 0xFFFF0000u);
            az1 += __uint_as_float(u1.y << 16); aw1 += __uint_as_float(u1.y & 0xFFFF0000u);
        }
        if (q2) {
            ax2 += __uint_as_float(u2.x << 16); ay2 += __uint_as_float(u2.x & 0xFFFF0000u);
            az2 += __uint_as_float(u2.y << 16); aw2 += __uint_as_float(u2.y & 0xFFFF0000u);
        }
    }
    float ax = (ax0 + ax1) + (ax2 + ax3);
    float ay = (ay0 + ay1) + (ay2 + ay3);
    float az = (az0 + az1) + (az2 + az3);
    float aw = (aw0 + aw1) + (aw2 + aw3);
    // combine the 4 groups (butterfly over lane bits 4,5)
    ax += __shfl_xor(ax, 16); ay += __shfl_xor(ay, 16);
    az += __shfl_xor(az, 16); aw += __shfl_xor(aw, 16);
    ax += __shfl_xor(ax, 32); ay += __shfl_xor(ay, 32);
    az += __shfl_xor(az, 32); aw += __shfl_xor(aw, 32);

    if (g == 0) {
        uint2 o;
        o.x = (unsigned)f2bf(ax) | ((unsigned)f2bf(ay) << 16);
        o.y = (unsigned)f2bf(az) | ((unsigned)f2bf(aw) << 16);
        *reinterpret_cast<uint2*>(aggb + (((size_t)(unsigned)n) << 6) + (j << 2)) = o;
    }
}

// ====== dense: y[n] = xb[n]@Ws + aggb[n]@Wm + b =============================
__global__ void __launch_bounds__(256)
dense_v3(const unsigned short* __restrict__ xb,
         const unsigned short* __restrict__ aggb,
         const float* __restrict__ Wself,
         const float* __restrict__ Wmsg,
         const float* __restrict__ bias,
         float* __restrict__ out_f32,
         unsigned short* __restrict__ out_bf16,
         int n_nodes, int last) {
    int lane = threadIdx.x & 63;
    int wave = threadIdx.x >> 6;
    int wpb = blockDim.x >> 6;

    float Wsc[D], Wmc[D];
#pragma unroll
    for (int k = 0; k < D; ++k) {
        Wsc[k] = Wself[k * D + lane];
        Wmc[k] = Wmsg[k * D + lane];
    }
    float bj = bias[lane];

    for (int n0 = blockIdx.x * wpb + wave; n0 < n_nodes; n0 += gridDim.x * wpb) {
        int n = __builtin_amdgcn_readfirstlane(n0);
        const unsigned* xrow = reinterpret_cast<const unsigned*>(xb)   + ((size_t)(unsigned)n << 5);
        const unsigned* arow = reinterpret_cast<const unsigned*>(aggb) + ((size_t)(unsigned)n << 5);

        float acc0 = bj, acc1 = 0.f, acc2 = 0.f, acc3 = 0.f;
#pragma unroll
        for (int dq = 0; dq < 32; dq += 2) {
            unsigned xu0 = xrow[dq], xu1 = xrow[dq + 1];
            unsigned au0 = arow[dq], au1 = arow[dq + 1];
            acc0 = fmaf(__uint_as_float(xu0 << 16),         Wsc[2 * dq + 0], acc0);
            acc1 = fmaf(__uint_as_float(xu0 & 0xFFFF0000u), Wsc[2 * dq + 1], acc1);
            acc2 = fmaf(__uint_as_float(xu1 << 16),         Wsc[2 * dq + 2], acc2);
            acc3 = fmaf(__uint_as_float(xu1 & 0xFFFF0000u), Wsc[2 * dq + 3], acc3);
            acc0 = fmaf(__uint_as_float(au0 << 16),         Wmc[2 * dq + 0], acc0);
            acc1 = fmaf(__uint_as_float(au0 & 0xFFFF0000u), Wmc[2 * dq + 1], acc1);
            acc2 = fmaf(__uint_as_float(au1 << 16),         Wmc[2 * dq + 2], acc2);
            acc3 = fmaf(__uint_as_float(au1 & 0xFFFF0000u), Wmc[2 * dq + 3], acc3);
        }
        float acc = (acc0 + acc1) + (acc2 + acc3);
        if (last) {
            out_f32[((size_t)(unsigned)n << 6) + lane] = acc;
        } else {
            out_bf16[((size_t)(unsigned)n << 6) + lane] = f2bf(fmaxf(acc, 0.f));
        }
    }
}

// ================= fallback (atomic path, fp32-exact) =======================
__global__ void scatter_kernel(const float* __restrict__ x,
                               const int* __restrict__ src,
                               const int* __restrict__ dst,
                               float* __restrict__ agg, int n_edges) {
    int e = blockIdx.x * (blockDim.x >> 6) + (threadIdx.x >> 6);
    int lane = threadIdx.x & 63;
    if (e >= n_edges) return;
    float v = x[(size_t)src[e] * D + lane];
    unsafeAtomicAdd(&agg[(size_t)dst[e] * D + lane], v);
}

__global__ void dense_kernel(const float* __restrict__ xin,
                             const float* __restrict__ agg,
                             const float* __restrict__ Wself,
                             const float* __restrict__ Wmsg,
                             const float* __restrict__ bias,
                             float* __restrict__ xout,
                             int n_nodes, int do_relu) {
    __shared__ float Ws[D * D];
    __shared__ float Wm[D * D];
    for (int i = threadIdx.x; i < D * D; i += blockDim.x) {
        Ws[i] = Wself[i];
        Wm[i] = Wmsg[i];
    }
    __syncthreads();
    int lane = threadIdx.x & 63;
    int wave = threadIdx.x >> 6;
    int wpb = blockDim.x >> 6;
    float bj = bias[lane];
    for (int n = blockIdx.x * wpb + wave; n < n_nodes; n += gridDim.x * wpb) {
        float xv = xin[(size_t)n * D + lane];
        float av = agg[(size_t)n * D + lane];
        float acc = bj;
#pragma unroll
        for (int k = 0; k < D; ++k) {
            acc += __shfl(xv, k, 64) * Ws[k * D + lane]
                 + __shfl(av, k, 64) * Wm[k * D + lane];
        }
        if (do_relu) acc = fmaxf(acc, 0.f);
        xout[(size_t)n * D + lane] = acc;
    }
}

// ============================================================================
extern "C" void kernel_launch(void* const* d_in, const int* in_sizes, int n_in,
                              void* d_out, int out_size, void* d_ws, size_t ws_size,
                              hipStream_t stream) {
    const float* x0    = (const float*)d_in[0];
    const int*   ei    = (const int*)d_in[1];
    const float* Wmsg  = (const float*)d_in[2];
    const float* Wself = (const float*)d_in[3];
    const float* bias  = (const float*)d_in[4];
    float* out = (float*)d_out;

    const int N = in_sizes[0] / D;         // 50000
    const int E = in_sizes[1] / 2;         // 800000
    const int n_layers = in_sizes[4] / D;  // 3

    const int* src = ei;
    const int* dst = ei + E;
    const size_t NB = (size_t)N * D * sizeof(float);

    const int NBB = (N + 255) / 256;
    const size_t need = (size_t)N * D * 2          // Xb
                      + (size_t)N * D * 2          // Aggb
                      + (size_t)E * 4              // sorted_src
                      + (size_t)E * 4              // rank
                      + (size_t)(N + 1) * 4        // row_ptr
                      + (size_t)N * 4              // deg
                      + (size_t)NBB * 4 * 2 + 256; // bsum + boff + slack

    if (ws_size >= need && NBB <= 1024) {
        char* p = (char*)d_ws;
        unsigned short* Xb   = (unsigned short*)p;  p += (size_t)N * D * 2;
        unsigned short* Aggb = (unsigned short*)p;  p += (size_t)N * D * 2;
        int* sorted_src      = (int*)p;             p += (size_t)E * 4;
        int* rank            = (int*)p;             p += (size_t)E * 4;
        int* row_ptr         = (int*)p;             p += (size_t)(N + 1) * 4;
        int* deg             = (int*)p;             p += (size_t)N * 4;
        int* bsum            = (int*)p;             p += (size_t)NBB * 4;
        int* boff            = (int*)p;

        {
            // prep: zero deg + convert x -> bf16 (fused, one dispatch)
            int total = N * D;
            int nthr = (total + 3) / 4;
            prep_kernel<<<(nthr + 255) / 256, 256, 0, stream>>>(x0, Xb, total, deg, N);

            int threads = 256;
            int nthr8 = (E + 7) / 8;
            int blocks = (nthr8 + threads - 1) / threads;
            hist_rank_kernel<<<blocks, threads, 0, stream>>>(dst, deg, rank, E);
            scan_k1<<<NBB, 256, 0, stream>>>(deg, bsum, N);
            scan_k2<<<1, 1024, 0, stream>>>(bsum, boff, NBB);
            scan_k3<<<NBB, 256, 0, stream>>>(deg, boff, row_ptr, N);
            perm_rank_kernel<<<blocks, threads, 0, stream>>>(src, dst, rank, row_ptr,
                                                             sorted_src, E);
        }

        const int gather_blocks = (N + 3) / 4;   // one wave per node
        const int dense_blocks = 1024;

        for (int layer = 0; layer < n_layers; ++layer) {
            gather_bf16<<<gather_blocks, 256, 0, stream>>>(Xb, row_ptr, sorted_src,
                                                           Aggb, N, E);
            dense_v3<<<dense_blocks, 256, 0, stream>>>(
                Xb, Aggb,
                Wself + (size_t)layer * D * D,
                Wmsg  + (size_t)layer * D * D,
                bias  + (size_t)layer * D,
                out, Xb, N, (layer == n_layers - 1) ? 1 : 0);
        }
    } else {
        // fallback: fp32 atomic path
        float* agg = (float*)d_ws;
        const int EPB = 256 / 64;
        const int scatter_blocks = (E + EPB - 1) / EPB;
        for (int layer = 0; layer < n_layers; ++layer) {
            hipMemsetAsync(agg, 0, NB, stream);
            const float* xin = (layer == 0) ? x0 : out;
            scatter_kernel<<<scatter_blocks, 256, 0, stream>>>(xin, src, dst, agg, E);
            dense_kernel<<<1024, 256, 0, stream>>>(
                xin, agg,
                Wself + (size_t)layer * D * D,
                Wmsg  + (size_t)layer * D * D,
                bias  + (size_t)layer * D,
                out, N, (layer < n_layers - 1) ? 1 : 0);
        }
    }
}